// Round 5
// baseline (516.416 us; speedup 1.0000x reference)
//
#include <hip/hip_runtime.h>
#include <math.h>

#define NC 21
#define NB 8
#define HW (512*512)
#define EPS 1e-8f
#define NREP 8
#define TPB 256
#define G4 2                                    // float4 groups per thread
#define F4_PER_BLOCK (TPB * G4)                 // 512 float4 = 2048 pixels
#define TILES_PER_IMG (HW / 4 / F4_PER_BLOCK)   // 128
#define NBLK (NB * TILES_PER_IMG)               // 1024
#define PSTRIDE 512

typedef float f32x4 __attribute__((ext_vector_type(4)));

// Round-6 = round-5 (plane-major restructure) with compile fixes.
// Theory recap: per-THREAD stream aliasing -- each thread's 21 plane addresses
// are identical in bits [0:19] (plane stride 1MB); every set-indexed structure
// on the load path (L1 sets, UTCL page slots, DRAM banks) sees 21-deep
// same-index aliasing that no issue-order change can fix (r2/r3 invariance at
// ~275us across VGPR 32/28/52, occ 38-57%). nt loads alone: 275->242us.
// Structural fix: walk planes one at a time (<=2 aliased streams in flight per
// thread), rotate plane start per block (bid % NC) so co-resident blocks
// stream DIFFERENT 1-MB regions device-wide.
// Argmax under rotated visitation: UPD keeps (max, smallest-index) -- order-
// independent, j init NC so ties at -inf also resolve to smallest c.

#define UPD(val, cc, mm, jj) \
    if ((val) > (mm) || ((val) == (mm) && (cc) < (jj))) { (mm) = (val); (jj) = (cc); }

template <bool PARTIAL>
__global__ __launch_bounds__(TPB) void cm_accum(const float* __restrict__ input,
                                                const float* __restrict__ target,
                                                float* __restrict__ cm /*[NB][NC][NC]*/,
                                                float* __restrict__ partial /*[NBLK][PSTRIDE]*/) {
    __shared__ float scm[NREP][NC * NC];
    const int t = threadIdx.x;
    for (int i = t; i < NREP * NC * NC; i += TPB) ((float*)scm)[i] = 0.0f;
    __syncthreads();

    const int bid  = blockIdx.x;
    const int b    = bid / TILES_PER_IMG;
    const int tile = bid % TILES_PER_IMG;
    const int rot  = bid % NC;                  // per-block plane rotation

    const f32x4* ip = (const f32x4*)(input  + (size_t)b * NC * HW);
    const f32x4* tp = (const f32x4*)(target + (size_t)b * NC * HW);
    const int plane4 = HW / 4;
    const int q0 = tile * F4_PER_BLOCK + t;     // group A at q0, group B at q0+TPB

    // ---- pass 1: argmax, plane-major, 1-plane-ahead pipeline ----
    f32x4 mA, mB;
    mA.x = mA.y = mA.z = mA.w = -INFINITY;
    mB.x = mB.y = mB.z = mB.w = -INFINITY;
    int jAx = NC, jAy = NC, jAz = NC, jAw = NC;
    int jBx = NC, jBy = NC, jBz = NC, jBw = NC;

    int c = rot;
    f32x4 curA = __builtin_nontemporal_load(ip + (size_t)c * plane4 + q0);
    f32x4 curB = __builtin_nontemporal_load(ip + (size_t)c * plane4 + q0 + TPB);
    f32x4 nxtA = {}, nxtB = {};
    for (int cc = 0; cc < NC; ++cc) {
        const int cn = (c + 1 == NC) ? 0 : c + 1;
        if (cc < NC - 1) {
            nxtA = __builtin_nontemporal_load(ip + (size_t)cn * plane4 + q0);
            nxtB = __builtin_nontemporal_load(ip + (size_t)cn * plane4 + q0 + TPB);
        }
        __builtin_amdgcn_sched_barrier(0);
        // consume plane c while plane cn's loads are in flight
        UPD(curA.x, c, mA.x, jAx); UPD(curA.y, c, mA.y, jAy);
        UPD(curA.z, c, mA.z, jAz); UPD(curA.w, c, mA.w, jAw);
        UPD(curB.x, c, mB.x, jBx); UPD(curB.y, c, mB.y, jBy);
        UPD(curB.z, c, mB.z, jBz); UPD(curB.w, c, mB.w, jBw);
        curA = nxtA; curB = nxtB;
        c = cn;
    }

    // ---- pass 2: target scatter, same plane walk ----
    float* my = scm[t & (NREP - 1)];
    c = rot;
    curA = __builtin_nontemporal_load(tp + (size_t)c * plane4 + q0);
    curB = __builtin_nontemporal_load(tp + (size_t)c * plane4 + q0 + TPB);
    for (int cc = 0; cc < NC; ++cc) {
        const int cn = (c + 1 == NC) ? 0 : c + 1;
        if (cc < NC - 1) {
            nxtA = __builtin_nontemporal_load(tp + (size_t)cn * plane4 + q0);
            nxtB = __builtin_nontemporal_load(tp + (size_t)cn * plane4 + q0 + TPB);
        }
        __builtin_amdgcn_sched_barrier(0);
        const int row = c * NC;
        atomicAdd(&my[row + jAx], curA.x);
        atomicAdd(&my[row + jAy], curA.y);
        atomicAdd(&my[row + jAz], curA.z);
        atomicAdd(&my[row + jAw], curA.w);
        atomicAdd(&my[row + jBx], curB.x);
        atomicAdd(&my[row + jBy], curB.y);
        atomicAdd(&my[row + jBz], curB.z);
        atomicAdd(&my[row + jBw], curB.w);
        curA = nxtA; curB = nxtB;
        c = cn;
    }
    __syncthreads();

    if (PARTIAL) {
        // contention-free flush to this block's own slice
        float* pout = partial + (size_t)bid * PSTRIDE;
        for (int i = t; i < PSTRIDE; i += TPB) {
            float s = 0.0f;
            if (i < NC * NC) {
                #pragma unroll
                for (int r = 0; r < NREP; ++r) s += scm[r][i];
            }
            pout[i] = s;   // pad region written as 0 -> reduce needs no guards
        }
    } else {
        for (int i = t; i < NC * NC; i += TPB) {
            float s = 0.0f;
            #pragma unroll
            for (int r = 0; r < NREP; ++r) s += scm[r][i];
            atomicAdd(&cm[b * NC * NC + i], s);
        }
    }
}

// partial[b*TILES_PER_IMG + s][e] summed over s -> cm[b][e]. 8 blocks.
__global__ __launch_bounds__(256) void cm_reduce(const float* __restrict__ partial,
                                                 float* __restrict__ cm) {
    const int b = blockIdx.x, t = threadIdx.x;
    const float* p = partial + (size_t)b * TILES_PER_IMG * PSTRIDE;
    float s0 = 0.0f, s1 = 0.0f;
    #pragma unroll 8
    for (int s = 0; s < TILES_PER_IMG; ++s) {
        s0 += p[(size_t)s * PSTRIDE + t];
        s1 += p[(size_t)s * PSTRIDE + t + 256];
    }
    cm[b * NC * NC + t] = s0;
    if (t + 256 < NC * NC) cm[b * NC * NC + t + 256] = s1;
}

// rowsum[b,i] = sum_j cm[b,i,j]; out[i,j] = mean_b cm[b,i,j]/(rowsum[b,i]+EPS)
__global__ __launch_bounds__(512) void cm_final(const float* __restrict__ cm,
                                                float* __restrict__ out) {
    __shared__ float rs[NB * NC];
    const int t = threadIdx.x;
    if (t < NB * NC) {
        const int b = t / NC, i = t % NC;
        float s = 0.0f;
        for (int j = 0; j < NC; ++j) s += cm[b * NC * NC + i * NC + j];
        rs[t] = s + EPS;
    }
    __syncthreads();
    if (t < NC * NC) {
        const int i = t / NC;
        float acc = 0.0f;
        for (int b = 0; b < NB; ++b) acc += cm[b * NC * NC + t] / rs[b * NC + i];
        out[t] = acc * (1.0f / NB);
    }
}

extern "C" void kernel_launch(void* const* d_in, const int* in_sizes, int n_in,
                              void* d_out, int out_size, void* d_ws, size_t ws_size,
                              hipStream_t stream) {
    const float* input  = (const float*)d_in[0];
    const float* target = (const float*)d_in[1];
    float* out = (float*)d_out;

    const size_t partial_floats = (size_t)NBLK * PSTRIDE;   // 512K floats = 2 MB
    const size_t need = (partial_floats + NB * NC * NC) * sizeof(float);

    if (ws_size >= need) {
        float* partial = (float*)d_ws;
        float* cm      = partial + partial_floats;
        cm_accum<true><<<NBLK, TPB, 0, stream>>>(input, target, cm, partial);
        cm_reduce<<<NB, 256, 0, stream>>>(partial, cm);
        cm_final<<<1, 512, 0, stream>>>(cm, out);
    } else {
        float* cm = (float*)d_ws;   // NB*NC*NC floats
        hipMemsetAsync(cm, 0, NB * NC * NC * sizeof(float), stream);
        cm_accum<false><<<NBLK, TPB, 0, stream>>>(input, target, cm, nullptr);
        cm_final<<<1, 512, 0, stream>>>(cm, out);
    }
}